// Round 11
// baseline (2048.478 us; speedup 1.0000x reference)
//
#include <hip/hip_runtime.h>
#include <stdint.h>

// ---------------- problem constants (fixed by the reference) ----------------
#define N_NODES   8000
#define N_EDGES   128000
#define WALK_LEN  16
#define OUT_DIM   8

// ---------------- main-kernel layout constants ----------------
#define WCOLS     16                   // walk columns per block (bf8 x16 = 16B rows)
#define NSLOT     8008                 // 8000 real rows + dummy zero-row 8000 (+pad)
#define PADCAP    (N_EDGES + 4 * N_NODES)  // 160000: per-col pad-to-4 worst case
#define SCALE     1024.0f

typedef _Float16 half2_t __attribute__((ext_vector_type(2)));

// bf8 = OCP e5m2 = top byte of f16. RNE quantize f32 -> e5m2 byte.
__device__ __forceinline__ uint32_t bf8q(float v) {
    uint16_t h = __builtin_bit_cast(uint16_t, (_Float16)v);
    return ((uint32_t)h + 0x7Fu + ((h >> 8) & 1u)) >> 8;
}
// exact decode e5m2 byte -> f32 (byte<<8 is a valid f16, incl. denormals)
__device__ __forceinline__ float bf8d(uint32_t b) {
    return (float)__builtin_bit_cast(_Float16, (uint16_t)(b << 8));
}

// ---------------- K0: init cnt/invdeg, fill prows with dummy row ----------------
__global__ void k0_init(uint32_t* __restrict__ cnt, float* __restrict__ invdeg,
                        uint16_t* __restrict__ prows) {
    int i = blockIdx.x * 256 + threadIdx.x;
    if (i < PADCAP)  prows[i] = (uint16_t)8000;   // dummy zero-row
    if (i < N_NODES) { cnt[i] = 0u; invdeg[i] = 1.0f; }
}

// ---------------- K1: in-degree count + invdeg scatter ----------------
// invdeg[r] = rw[e] for every edge with row r (all identical: 1/deg(r)) — benign race.
__global__ void k1_count(const int* __restrict__ ei, const float* __restrict__ rw,
                         uint32_t* __restrict__ cnt, float* __restrict__ invdeg) {
    int e = blockIdx.x * 256 + threadIdx.x;
    if (e < N_EDGES) {
        int r = ei[e];
        int c = ei[N_EDGES + e];
        atomicAdd(&cnt[c], 1u);
        invdeg[r] = rw[e];
    }
}

// ---------------- K2: counting sort of columns by in-degree ----------------
// perm[slot] = col, rank[col] = slot.  Sorted order = wave-uniform trip counts.
__global__ __launch_bounds__(1024) void k2_sort(const uint32_t* __restrict__ cnt,
                                                uint32_t* __restrict__ perm,
                                                uint32_t* __restrict__ rank) {
    __shared__ uint32_t h[256];
    __shared__ uint32_t hoff[256];
    int t = threadIdx.x;
    if (t < 256) h[t] = 0u;
    __syncthreads();
    for (int i = t; i < N_NODES; i += 1024) {
        uint32_t d = cnt[i]; if (d > 255u) d = 255u;
        atomicAdd(&h[d], 1u);
    }
    __syncthreads();
    if (t == 0) {
        uint32_t run = 0;
        for (int b = 0; b < 256; ++b) { hoff[b] = run; run += h[b]; }
    }
    __syncthreads();
    for (int i = t; i < N_NODES; i += 1024) {
        uint32_t d = cnt[i]; if (d > 255u) d = 255u;
        uint32_t slot = atomicAdd(&hoff[d], 1u);
        perm[slot] = (uint32_t)i;
        rank[i] = slot;
    }
}

// ---------------- K3: exclusive scan of pad-to-4 degrees over perm order ----------------
__global__ __launch_bounds__(1024) void k3_scan(const uint32_t* __restrict__ cnt,
                                                const uint32_t* __restrict__ perm,
                                                uint32_t* __restrict__ poffs,
                                                uint32_t* __restrict__ pcur) {
    __shared__ uint32_t s[2][8192];   // 64 KB, Hillis-Steele double buffer
    int t = threadIdx.x;
    for (int i = t; i < 8192; i += 1024) {
        uint32_t v = 0u;
        if (i < N_NODES) v = (cnt[perm[i]] + 3u) & ~3u;   // pad each column to x4
        s[0][i] = v;
    }
    __syncthreads();
    int src = 0;
    for (int d = 1; d < 8192; d <<= 1) {
        for (int i = t; i < 8192; i += 1024) {
            uint32_t v = s[src][i];
            if (i >= d) v += s[src][i - d];
            s[src ^ 1][i] = v;
        }
        __syncthreads();
        src ^= 1;
    }
    for (int i = t; i < 8192; i += 1024) {
        if (i < N_NODES) {
            uint32_t ex = (i == 0) ? 0u : s[src][i - 1];
            poffs[i] = ex;
            pcur[i]  = ex;
        }
    }
    if (t == 0) poffs[N_NODES] = s[src][N_NODES - 1];
}

// ---------------- K4: scatter edges into permuted CSC (plain u16 row index) ------------
// NOTE: edge order within a column is arrival-random — measured better than any
// correlated stagger sort (round-8 post-mortem: k4b was 2x WORSE than random).
__global__ void k4_scatter(const int* __restrict__ ei, const uint32_t* __restrict__ rank,
                           uint32_t* __restrict__ pcur, uint16_t* __restrict__ prows) {
    int e = blockIdx.x * 256 + threadIdx.x;
    if (e < N_EDGES) {
        int r = ei[e];
        int c = ei[N_EDGES + e];
        uint32_t slot = rank[c];
        uint32_t pos  = atomicAdd(&pcur[slot], 1u);
        prows[pos] = (uint16_t)r;
    }
}

// ---------------- K5: the 16-step walk, 16 columns per block, bf8 state ------------
// State X~ = q_bf8(SCALE * invdeg ⊙ X) in 16-byte rows, SINGLE LDS buffer.
// Per step: gather old state into f32 accs (b128 reads, bf8 decode via byte<<8=f16),
// barrier, write re-quantized rows back, barrier.
// diag_s[c] = acc[c] * invdeg[c] / d0[c]  (d0 = decoded quantized init: exact
// cancellation of the systematic init-quantization scale error).
__global__ __launch_bounds__(1024, 4) void k5_walk(const uint32_t* __restrict__ perm,
                                                   const uint32_t* __restrict__ poffs,
                                                   const uint16_t* __restrict__ prows,
                                                   const float* __restrict__ invdeg,
                                                   float* __restrict__ diag) {
    __shared__ uint4 Xs[NSLOT];   // 128128 bytes static LDS
    const int t  = threadIdx.x;
    const int c0 = blockIdx.x * WCOLS;

    // zero the buffer (dummy row 8000 stays zero forever)
    for (int i = t; i < NSLOT; i += 1024) Xs[i] = make_uint4(0u, 0u, 0u, 0u);
    __syncthreads();
    if (t < WCOLS) {
        int c = c0 + t;
        uint32_t q = bf8q(invdeg[c] * SCALE);   // scaled one-hot, weight pre-folded
        ((uint8_t*)&Xs[0])[c * 16 + t] = (uint8_t)q;   // col t = byte t of row c
    }

    // cache this thread's 8 slots in registers for all 16 steps
    uint32_t sc[8], sb[8], se[8];
    float sid[8], dsc[8];
#pragma unroll
    for (int q = 0; q < 8; ++q) {
        int i = q * 1024 + t;
        if (i < N_NODES) {
            uint32_t c = perm[i];
            sc[q] = c;
            sb[q] = poffs[i];
            se[q] = poffs[i + 1];
            float id = invdeg[c];
            sid[q] = id;
            uint32_t j = c - (uint32_t)c0;
            dsc[q] = (j < WCOLS) ? (id / bf8d(bf8q(id * SCALE))) : 0.0f;
        } else {
            sc[q] = 0xFFFFFFFFu; sb[q] = 0u; se[q] = 0u; sid[q] = 0.0f; dsc[q] = 0.0f;
        }
    }
    __syncthreads();

    const char* base = (const char*)&Xs[0];

    for (int s = 0; s < WALK_LEN; ++s) {
        uint4 pend[8];
#pragma unroll
        for (int q = 0; q < 8; ++q) {
            if (sc[q] == 0xFFFFFFFFu) { pend[q] = make_uint4(0u, 0u, 0u, 0u); continue; }
            float a0 = 0.f, a1 = 0.f, a2 = 0.f, a3 = 0.f;
            float a4 = 0.f, a5 = 0.f, a6 = 0.f, a7 = 0.f;
            float a8 = 0.f, a9 = 0.f, a10 = 0.f, a11 = 0.f;
            float a12 = 0.f, a13 = 0.f, a14 = 0.f, a15 = 0.f;
            for (uint32_t e = sb[q]; e < se[q]; e += 4) {
                uint2 cc = *(const uint2*)(prows + e);   // 4 u16 row indices
// 4 bf8 bytes of word W -> two f16-pairs via v_perm (one inst each), then cvt+add
#define DEC4(W, pA, pB, pC, pD)                                             \
                {   uint32_t lo = __byte_perm((W), 0u, 0x1404u);            \
                    uint32_t hi = __byte_perm((W), 0u, 0x3424u);            \
                    half2_t hl = __builtin_bit_cast(half2_t, lo);           \
                    half2_t hh = __builtin_bit_cast(half2_t, hi);           \
                    pA += (float)hl.x;  pB += (float)hl.y;                  \
                    pC += (float)hh.x;  pD += (float)hh.y;  }
#define EDGE_AT(R)                                                          \
                {   uint4 wv = *(const uint4*)(base + ((uint32_t)(R) << 4));\
                    DEC4(wv.x, a0,  a1,  a2,  a3 )                          \
                    DEC4(wv.y, a4,  a5,  a6,  a7 )                          \
                    DEC4(wv.z, a8,  a9,  a10, a11)                          \
                    DEC4(wv.w, a12, a13, a14, a15) }
                EDGE_AT(cc.x & 0xFFFFu)  EDGE_AT(cc.x >> 16)
                EDGE_AT(cc.y & 0xFFFFu)  EDGE_AT(cc.y >> 16)
#undef EDGE_AT
#undef DEC4
            }
            uint32_t c = sc[q];
            uint32_t j = c - (uint32_t)c0;
            if (j < (uint32_t)WCOLS) {   // own-column diagonal, exact init-scale correction
                float dv = a0;
                dv = (j == 1u)  ? a1  : dv;  dv = (j == 2u)  ? a2  : dv;
                dv = (j == 3u)  ? a3  : dv;  dv = (j == 4u)  ? a4  : dv;
                dv = (j == 5u)  ? a5  : dv;  dv = (j == 6u)  ? a6  : dv;
                dv = (j == 7u)  ? a7  : dv;  dv = (j == 8u)  ? a8  : dv;
                dv = (j == 9u)  ? a9  : dv;  dv = (j == 10u) ? a10 : dv;
                dv = (j == 11u) ? a11 : dv;  dv = (j == 12u) ? a12 : dv;
                dv = (j == 13u) ? a13 : dv;  dv = (j == 14u) ? a14 : dv;
                dv = (j == 15u) ? a15 : dv;
                diag[c * WALK_LEN + s] = dv * dsc[q];
            }
            float id = sid[q];
            uint32_t w0 = bf8q(a0  * id) | (bf8q(a1  * id) << 8) |
                          (bf8q(a2  * id) << 16) | (bf8q(a3  * id) << 24);
            uint32_t w1 = bf8q(a4  * id) | (bf8q(a5  * id) << 8) |
                          (bf8q(a6  * id) << 16) | (bf8q(a7  * id) << 24);
            uint32_t w2 = bf8q(a8  * id) | (bf8q(a9  * id) << 8) |
                          (bf8q(a10 * id) << 16) | (bf8q(a11 * id) << 24);
            uint32_t w3 = bf8q(a12 * id) | (bf8q(a13 * id) << 8) |
                          (bf8q(a14 * id) << 16) | (bf8q(a15 * id) << 24);
            pend[q] = make_uint4(w0, w1, w2, w3);
        }
        __syncthreads();   // all reads of old state done
#pragma unroll
        for (int q = 0; q < 8; ++q)
            if (sc[q] != 0xFFFFFFFFu) Xs[sc[q]] = pend[q];
        __syncthreads();   // new state visible
    }
}

// ---------------- K6: linear layer out = diag @ W^T + b ----------------
__global__ void k6_out(const float* __restrict__ diag, const float* __restrict__ W,
                       const float* __restrict__ b, float* __restrict__ out) {
    int i = blockIdx.x * 256 + threadIdx.x;
    if (i < N_NODES * OUT_DIM) {
        int n = i >> 3;
        int d = i & 7;
        float acc = b[d];
#pragma unroll
        for (int k = 0; k < WALK_LEN; ++k)
            acc += diag[n * WALK_LEN + k] * W[d * WALK_LEN + k];
        out[i] = acc;
    }
}

// ---------------- launcher ----------------
extern "C" void kernel_launch(void* const* d_in, const int* in_sizes, int n_in,
                              void* d_out, int out_size, void* d_ws, size_t ws_size,
                              hipStream_t stream) {
    const int*   ei = (const int*)d_in[0];     // [2, E] int32: rows then cols
    const float* rw = (const float*)d_in[2];   // [E] f32
    const float* W  = (const float*)d_in[3];   // [8,16] f32
    const float* b  = (const float*)d_in[4];   // [8] f32
    float* out = (float*)d_out;                // [N,8] f32

    // workspace carve-up (512-byte aligned slices)
    char* w = (char*)d_ws;
    auto alloc = [&](size_t bytes) -> char* {
        char* p = w;
        w += (bytes + 511) & ~(size_t)511;
        return p;
    };
    uint32_t* cnt    = (uint32_t*)alloc(N_NODES * 4);
    float*    invdeg = (float*)   alloc(N_NODES * 4);
    uint32_t* perm   = (uint32_t*)alloc(N_NODES * 4);
    uint32_t* rank   = (uint32_t*)alloc(N_NODES * 4);
    uint32_t* poffs  = (uint32_t*)alloc((N_NODES + 1) * 4);
    uint32_t* pcur   = (uint32_t*)alloc(N_NODES * 4);
    uint16_t* prows  = (uint16_t*)alloc(PADCAP * 2);
    float*    diag   = (float*)   alloc(N_NODES * WALK_LEN * 4);

    k0_init   <<<(PADCAP + 255) / 256, 256, 0, stream>>>(cnt, invdeg, prows);
    k1_count  <<<(N_EDGES + 255) / 256, 256, 0, stream>>>(ei, rw, cnt, invdeg);
    k2_sort   <<<1, 1024, 0, stream>>>(cnt, perm, rank);
    k3_scan   <<<1, 1024, 0, stream>>>(cnt, perm, poffs, pcur);
    k4_scatter<<<(N_EDGES + 255) / 256, 256, 0, stream>>>(ei, rank, pcur, prows);
    k5_walk   <<<N_NODES / WCOLS, 1024, 0, stream>>>(perm, poffs, prows, invdeg, diag);
    k6_out    <<<(N_NODES * OUT_DIM + 255) / 256, 256, 0, stream>>>(diag, W, b, out);
}

// Round 12
// 1694.845 us; speedup vs baseline: 1.2087x; 1.2087x over previous
//
#include <hip/hip_runtime.h>
#include <stdint.h>

// ---------------- problem constants (fixed by the reference) ----------------
#define N_NODES   8000
#define N_EDGES   128000
#define WALK_LEN  16
#define OUT_DIM   8

// ---------------- main-kernel layout constants ----------------
#define WCOLS     16                   // walk columns per block (bf8 x16 = 16B rows)
#define NSLOT     8008                 // 8000 real rows + dummy zero-row 8000 (+pad)
#define PADCAP    (N_EDGES + 4 * N_NODES)  // 160000: per-col pad-to-4 worst case
#define SCALE     1024.0f

typedef _Float16       half2_t  __attribute__((ext_vector_type(2)));
typedef unsigned short ushort2_t __attribute__((ext_vector_type(2)));

// bf8 = OCP e5m2 = top byte of f16. RNE quantize f32 -> e5m2 byte (scalar, prep only).
__device__ __forceinline__ uint32_t bf8q(float v) {
    uint16_t h = __builtin_bit_cast(uint16_t, (_Float16)v);
    return ((uint32_t)h + 0x7Fu + ((h >> 8) & 1u)) >> 8;
}
// exact decode e5m2 byte -> f32 (byte<<8 is a valid f16, incl. denormals)
__device__ __forceinline__ float bf8d(uint32_t b) {
    return (float)__builtin_bit_cast(_Float16, (uint16_t)(b << 8));
}
// packed: quantize 2 cols (f16 pair * idh pair) -> u32 with bytes [q0,0,q1,0]
__device__ __forceinline__ uint32_t qpair(half2_t a, half2_t idh) {
    half2_t v = a * idh;                               // v_pk_mul_f16 (RNE)
    ushort2_t h = __builtin_bit_cast(ushort2_t, v);
    ushort2_t one  = {1, 1};
    ushort2_t c7f  = {0x7F, 0x7F};
    ushort2_t r = (h >> 8) & one;                      // RNE tie bit
    ushort2_t t = h + r + c7f;                         // v_pk_add_u16 (per-lane wrap)
    ushort2_t q = t >> 8;                              // v_pk_lshrrev_b16
    return __builtin_bit_cast(uint32_t, q);
}

// ---------------- K0: init cnt/invdeg, fill prows with dummy row ----------------
__global__ void k0_init(uint32_t* __restrict__ cnt, float* __restrict__ invdeg,
                        uint16_t* __restrict__ prows) {
    int i = blockIdx.x * 256 + threadIdx.x;
    if (i < PADCAP)  prows[i] = (uint16_t)8000;   // dummy zero-row
    if (i < N_NODES) { cnt[i] = 0u; invdeg[i] = 1.0f; }
}

// ---------------- K1: in-degree count + invdeg scatter ----------------
__global__ void k1_count(const int* __restrict__ ei, const float* __restrict__ rw,
                         uint32_t* __restrict__ cnt, float* __restrict__ invdeg) {
    int e = blockIdx.x * 256 + threadIdx.x;
    if (e < N_EDGES) {
        int r = ei[e];
        int c = ei[N_EDGES + e];
        atomicAdd(&cnt[c], 1u);
        invdeg[r] = rw[e];   // all writers write the same value — benign race
    }
}

// ---------------- K2: counting sort of columns by in-degree ----------------
__global__ __launch_bounds__(1024) void k2_sort(const uint32_t* __restrict__ cnt,
                                                uint32_t* __restrict__ perm,
                                                uint32_t* __restrict__ rank) {
    __shared__ uint32_t h[256];
    __shared__ uint32_t hoff[256];
    int t = threadIdx.x;
    if (t < 256) h[t] = 0u;
    __syncthreads();
    for (int i = t; i < N_NODES; i += 1024) {
        uint32_t d = cnt[i]; if (d > 255u) d = 255u;
        atomicAdd(&h[d], 1u);
    }
    __syncthreads();
    if (t == 0) {
        uint32_t run = 0;
        for (int b = 0; b < 256; ++b) { hoff[b] = run; run += h[b]; }
    }
    __syncthreads();
    for (int i = t; i < N_NODES; i += 1024) {
        uint32_t d = cnt[i]; if (d > 255u) d = 255u;
        uint32_t slot = atomicAdd(&hoff[d], 1u);
        perm[slot] = (uint32_t)i;
        rank[i] = slot;
    }
}

// ---------------- K2b: per-slot walk descriptors (idp = dup'd f16 invdeg; dscp) ------
__global__ void k2b_prep(const uint32_t* __restrict__ perm, const float* __restrict__ invdeg,
                         uint32_t* __restrict__ idp, float* __restrict__ dscp) {
    int i = blockIdx.x * 256 + threadIdx.x;
    if (i < N_NODES) {
        float id = invdeg[perm[i]];
        uint32_t h = (uint32_t)__builtin_bit_cast(uint16_t, (_Float16)id);
        idp[i]  = h | (h << 16);
        dscp[i] = id / bf8d(bf8q(id * SCALE));   // exact init-quantization correction
    }
}

// ---------------- K3: exclusive scan of pad-to-4 degrees over perm order -------------
__global__ __launch_bounds__(1024) void k3_scan(const uint32_t* __restrict__ cnt,
                                                const uint32_t* __restrict__ perm,
                                                uint32_t* __restrict__ poffs,
                                                uint32_t* __restrict__ pcur) {
    __shared__ uint32_t s[2][8192];
    int t = threadIdx.x;
    for (int i = t; i < 8192; i += 1024) {
        uint32_t v = 0u;
        if (i < N_NODES) v = (cnt[perm[i]] + 3u) & ~3u;
        s[0][i] = v;
    }
    __syncthreads();
    int src = 0;
    for (int d = 1; d < 8192; d <<= 1) {
        for (int i = t; i < 8192; i += 1024) {
            uint32_t v = s[src][i];
            if (i >= d) v += s[src][i - d];
            s[src ^ 1][i] = v;
        }
        __syncthreads();
        src ^= 1;
    }
    for (int i = t; i < 8192; i += 1024) {
        if (i < N_NODES) {
            uint32_t ex = (i == 0) ? 0u : s[src][i - 1];
            poffs[i] = ex;
            pcur[i]  = ex;
        }
    }
    if (t == 0) poffs[N_NODES] = s[src][N_NODES - 1];
}

// ---------------- K4: scatter edges into permuted CSC (arrival-random order) ---------
__global__ void k4_scatter(const int* __restrict__ ei, const uint32_t* __restrict__ rank,
                           uint32_t* __restrict__ pcur, uint16_t* __restrict__ prows) {
    int e = blockIdx.x * 256 + threadIdx.x;
    if (e < N_EDGES) {
        int r = ei[e];
        int c = ei[N_EDGES + e];
        uint32_t slot = rank[c];
        uint32_t pos  = atomicAdd(&pcur[slot], 1u);
        prows[pos] = (uint16_t)r;
    }
}

// ---------------- K5: 16-step walk, 16 cols/block, bf8 state, PACKED f16 math --------
// Per edge: ds_read_b128 + (2 byte_perm + 2 v_pk_add_f16) x4 words.
// Re-quantize: packed u16 rounding (qpair) + 1 byte_perm per word.
__global__ __launch_bounds__(1024, 4) void k5_walk(const uint32_t* __restrict__ perm,
                                                   const uint32_t* __restrict__ poffs,
                                                   const uint16_t* __restrict__ prows,
                                                   const float* __restrict__ invdeg,
                                                   const uint32_t* __restrict__ idp,
                                                   const float* __restrict__ dscp,
                                                   float* __restrict__ diag) {
    __shared__ uint4 Xs[NSLOT];   // 128128 bytes static LDS
    const int t  = threadIdx.x;
    const int c0 = blockIdx.x * WCOLS;

    for (int i = t; i < NSLOT; i += 1024) Xs[i] = make_uint4(0u, 0u, 0u, 0u);
    __syncthreads();
    if (t < WCOLS) {
        int c = c0 + t;
        uint32_t q = bf8q(invdeg[c] * SCALE);          // scaled one-hot, weight pre-folded
        ((uint8_t*)&Xs[0])[c * 16 + t] = (uint8_t)q;   // col t = byte t of row c
    }

    // per-thread slot cache: 4 x 8 = 32 VGPRs
    uint32_t sc[8], sb[8], se[8], sip[8];
#pragma unroll
    for (int q = 0; q < 8; ++q) {
        int i = q * 1024 + t;
        if (i < N_NODES) {
            sc[q] = perm[i];
            sb[q] = poffs[i];
            se[q] = poffs[i + 1];
            sip[q] = idp[i];
        } else {
            sc[q] = 0xFFFFFFFFu; sb[q] = 0u; se[q] = 0u; sip[q] = 0u;
        }
    }
    __syncthreads();

    const char* base = (const char*)&Xs[0];
    const half2_t hz = {(_Float16)0.0f, (_Float16)0.0f};

    for (int s = 0; s < WALK_LEN; ++s) {
        uint4 pend[8];
#pragma unroll
        for (int q = 0; q < 8; ++q) {
            if (sc[q] == 0xFFFFFFFFu) { pend[q] = make_uint4(0u, 0u, 0u, 0u); continue; }
            half2_t p0 = hz, p1 = hz, p2 = hz, p3 = hz;
            half2_t p4 = hz, p5 = hz, p6 = hz, p7 = hz;
            for (uint32_t e = sb[q]; e < se[q]; e += 4) {
                uint2 cc = *(const uint2*)(prows + e);   // 4 u16 row indices
// word W (4 bf8 bytes) -> two f16 pairs via byte_perm, accumulate with v_pk_add_f16
#define DEC4P(W, PA, PB)                                                    \
                {   uint32_t lo = __byte_perm((W), 0u, 0x1404u);            \
                    uint32_t hi = __byte_perm((W), 0u, 0x3424u);            \
                    PA += __builtin_bit_cast(half2_t, lo);                  \
                    PB += __builtin_bit_cast(half2_t, hi);  }
#define EDGE_AT(R)                                                          \
                {   uint4 wv = *(const uint4*)(base + ((uint32_t)(R) << 4));\
                    DEC4P(wv.x, p0, p1)  DEC4P(wv.y, p2, p3)                \
                    DEC4P(wv.z, p4, p5)  DEC4P(wv.w, p6, p7)  }
                EDGE_AT(cc.x & 0xFFFFu)  EDGE_AT(cc.x >> 16)
                EDGE_AT(cc.y & 0xFFFFu)  EDGE_AT(cc.y >> 16)
#undef EDGE_AT
#undef DEC4P
            }
            uint32_t c = sc[q];
            uint32_t j = c - (uint32_t)c0;
            if (j < (uint32_t)WCOLS) {   // own-column diagonal (init-scale corrected)
                uint32_t pj = j >> 1;    // static-select the pair (no runtime indexing)
                half2_t sp = p0;
                sp = (pj == 1u) ? p1 : sp;  sp = (pj == 2u) ? p2 : sp;
                sp = (pj == 3u) ? p3 : sp;  sp = (pj == 4u) ? p4 : sp;
                sp = (pj == 5u) ? p5 : sp;  sp = (pj == 6u) ? p6 : sp;
                sp = (pj == 7u) ? p7 : sp;
                float lo = (float)sp.x, hi = (float)sp.y;
                float dv = (j & 1u) ? hi : lo;
                diag[c * WALK_LEN + s] = dv * dscp[q * 1024 + t];
            }
            half2_t idh = __builtin_bit_cast(half2_t, sip[q]);
            pend[q].x = __byte_perm(qpair(p0, idh), qpair(p1, idh), 0x6420u);
            pend[q].y = __byte_perm(qpair(p2, idh), qpair(p3, idh), 0x6420u);
            pend[q].z = __byte_perm(qpair(p4, idh), qpair(p5, idh), 0x6420u);
            pend[q].w = __byte_perm(qpair(p6, idh), qpair(p7, idh), 0x6420u);
        }
        __syncthreads();   // all reads of old state done
#pragma unroll
        for (int q = 0; q < 8; ++q)
            if (sc[q] != 0xFFFFFFFFu) Xs[sc[q]] = pend[q];
        __syncthreads();   // new state visible
    }
}

// ---------------- K6: linear layer out = diag @ W^T + b ----------------
__global__ void k6_out(const float* __restrict__ diag, const float* __restrict__ W,
                       const float* __restrict__ b, float* __restrict__ out) {
    int i = blockIdx.x * 256 + threadIdx.x;
    if (i < N_NODES * OUT_DIM) {
        int n = i >> 3;
        int d = i & 7;
        float acc = b[d];
#pragma unroll
        for (int k = 0; k < WALK_LEN; ++k)
            acc += diag[n * WALK_LEN + k] * W[d * WALK_LEN + k];
        out[i] = acc;
    }
}

// ---------------- launcher ----------------
extern "C" void kernel_launch(void* const* d_in, const int* in_sizes, int n_in,
                              void* d_out, int out_size, void* d_ws, size_t ws_size,
                              hipStream_t stream) {
    const int*   ei = (const int*)d_in[0];     // [2, E] int32: rows then cols
    const float* rw = (const float*)d_in[2];   // [E] f32
    const float* W  = (const float*)d_in[3];   // [8,16] f32
    const float* b  = (const float*)d_in[4];   // [8] f32
    float* out = (float*)d_out;                // [N,8] f32

    char* w = (char*)d_ws;
    auto alloc = [&](size_t bytes) -> char* {
        char* p = w;
        w += (bytes + 511) & ~(size_t)511;
        return p;
    };
    uint32_t* cnt    = (uint32_t*)alloc(N_NODES * 4);
    float*    invdeg = (float*)   alloc(N_NODES * 4);
    uint32_t* perm   = (uint32_t*)alloc(N_NODES * 4);
    uint32_t* rank   = (uint32_t*)alloc(N_NODES * 4);
    uint32_t* poffs  = (uint32_t*)alloc((N_NODES + 1) * 4);
    uint32_t* pcur   = (uint32_t*)alloc(N_NODES * 4);
    uint32_t* idp    = (uint32_t*)alloc(N_NODES * 4);
    float*    dscp   = (float*)   alloc(N_NODES * 4);
    uint16_t* prows  = (uint16_t*)alloc(PADCAP * 2);
    float*    diag   = (float*)   alloc(N_NODES * WALK_LEN * 4);

    k0_init   <<<(PADCAP + 255) / 256, 256, 0, stream>>>(cnt, invdeg, prows);
    k1_count  <<<(N_EDGES + 255) / 256, 256, 0, stream>>>(ei, rw, cnt, invdeg);
    k2_sort   <<<1, 1024, 0, stream>>>(cnt, perm, rank);
    k2b_prep  <<<(N_NODES + 255) / 256, 256, 0, stream>>>(perm, invdeg, idp, dscp);
    k3_scan   <<<1, 1024, 0, stream>>>(cnt, perm, poffs, pcur);
    k4_scatter<<<(N_EDGES + 255) / 256, 256, 0, stream>>>(ei, rank, pcur, prows);
    k5_walk   <<<N_NODES / WCOLS, 1024, 0, stream>>>(perm, poffs, prows, invdeg,
                                                     idp, dscp, diag);
    k6_out    <<<(N_NODES * OUT_DIM + 255) / 256, 256, 0, stream>>>(diag, W, b, out);
}

// Round 13
// 1429.081 us; speedup vs baseline: 1.4334x; 1.1860x over previous
//
#include <hip/hip_runtime.h>
#include <stdint.h>

// ---------------- problem constants (fixed by the reference) ----------------
#define N_NODES   8000
#define N_EDGES   128000
#define WALK_LEN  16
#define OUT_DIM   8

// ---------------- main-kernel layout constants ----------------
#define WCOLS     8                    // walk columns per block (f16x8 = 16B rows)
#define NSLOT     8008                 // 8000 real rows + dummy zero-row 8000 (+pad)
#define PADCAP    (N_EDGES + 4 * N_NODES)  // 160000: per-col pad-to-4 worst case

typedef _Float16 half2_t __attribute__((ext_vector_type(2)));

// ---------------- K0: init cnt/invdeg, fill prows with the dummy row ----------------
// All pad edges point at row 8000 (kept zero): a wave's pad lanes read the SAME
// address -> LDS broadcast, no bank conflict.
__global__ void k0_init(uint32_t* __restrict__ cnt, float* __restrict__ invdeg,
                        uint16_t* __restrict__ prows) {
    int i = blockIdx.x * 256 + threadIdx.x;
    if (i < PADCAP)  prows[i] = (uint16_t)8000;
    if (i < N_NODES) { cnt[i] = 0u; invdeg[i] = 1.0f; }
}

// ---------------- K1: in-degree count + invdeg scatter ----------------
// invdeg[r] = rw[e] for every edge with row r (all identical: 1/deg(r)) — benign race.
// Nodes with no out-edges keep invdeg=1.0, matching the reference's clip(deg,1).
__global__ void k1_count(const int* __restrict__ ei, const float* __restrict__ rw,
                         uint32_t* __restrict__ cnt, float* __restrict__ invdeg) {
    int e = blockIdx.x * 256 + threadIdx.x;
    if (e < N_EDGES) {
        int r = ei[e];
        int c = ei[N_EDGES + e];
        atomicAdd(&cnt[c], 1u);
        invdeg[r] = rw[e];
    }
}

// ---------------- K2: counting sort of columns by in-degree ----------------
// perm[slot] = col, rank[col] = slot.  Sorted order = wave-uniform trip counts.
__global__ __launch_bounds__(1024) void k2_sort(const uint32_t* __restrict__ cnt,
                                                uint32_t* __restrict__ perm,
                                                uint32_t* __restrict__ rank) {
    __shared__ uint32_t h[256];
    __shared__ uint32_t hoff[256];
    int t = threadIdx.x;
    if (t < 256) h[t] = 0u;
    __syncthreads();
    for (int i = t; i < N_NODES; i += 1024) {
        uint32_t d = cnt[i]; if (d > 255u) d = 255u;
        atomicAdd(&h[d], 1u);
    }
    __syncthreads();
    if (t == 0) {
        uint32_t run = 0;
        for (int b = 0; b < 256; ++b) { hoff[b] = run; run += h[b]; }
    }
    __syncthreads();
    for (int i = t; i < N_NODES; i += 1024) {
        uint32_t d = cnt[i]; if (d > 255u) d = 255u;
        uint32_t slot = atomicAdd(&hoff[d], 1u);
        perm[slot] = (uint32_t)i;
        rank[i] = slot;
    }
}

// ---------------- K3: exclusive scan of pad-to-4 degrees over perm order ----------------
__global__ __launch_bounds__(1024) void k3_scan(const uint32_t* __restrict__ cnt,
                                                const uint32_t* __restrict__ perm,
                                                uint32_t* __restrict__ poffs,
                                                uint32_t* __restrict__ pcur) {
    __shared__ uint32_t s[2][8192];   // 64 KB, Hillis-Steele double buffer
    int t = threadIdx.x;
    for (int i = t; i < 8192; i += 1024) {
        uint32_t v = 0u;
        if (i < N_NODES) v = (cnt[perm[i]] + 3u) & ~3u;   // pad each column to x4
        s[0][i] = v;
    }
    __syncthreads();
    int src = 0;
    for (int d = 1; d < 8192; d <<= 1) {
        for (int i = t; i < 8192; i += 1024) {
            uint32_t v = s[src][i];
            if (i >= d) v += s[src][i - d];
            s[src ^ 1][i] = v;
        }
        __syncthreads();
        src ^= 1;
    }
    for (int i = t; i < 8192; i += 1024) {
        if (i < N_NODES) {
            uint32_t ex = (i == 0) ? 0u : s[src][i - 1];
            poffs[i] = ex;
            pcur[i]  = ex;
        }
    }
    if (t == 0) poffs[N_NODES] = s[src][N_NODES - 1];
}

// ---------------- K4: scatter edges into permuted CSC (plain u16 row index) ------------
// Edge order within a column is arrival-random — measured BEST (round 12: 8.1
// conflict-cyc/read vs 10.8 for the k4b stagger sort; k4b removed permanently).
__global__ void k4_scatter(const int* __restrict__ ei, const uint32_t* __restrict__ rank,
                           uint32_t* __restrict__ pcur, uint16_t* __restrict__ prows) {
    int e = blockIdx.x * 256 + threadIdx.x;
    if (e < N_EDGES) {
        int r = ei[e];
        int c = ei[N_EDGES + e];
        uint32_t slot = rank[c];
        uint32_t pos  = atomicAdd(&pcur[slot], 1u);
        prows[pos] = (uint16_t)r;
    }
}

// ---------------- K5: the 16-step walk, 8 columns per block, reg ping-pong ------------
// State X~ = 1024 * invdeg ⊙ X in f16x8 rows (16B), SINGLE LDS buffer (128128 B).
// Per step: gather old state into f32 accs (b128 reads), hold new rows in VGPRs,
// barrier, write back, barrier.  diag_s = acc/1024 at own column.
// (Model-verified structure: round 8 measured 25.5 cyc/read vs 22.8 modeled.)
__global__ __launch_bounds__(1024, 4) void k5_walk(const uint32_t* __restrict__ perm,
                                                   const uint32_t* __restrict__ poffs,
                                                   const uint16_t* __restrict__ prows,
                                                   const float* __restrict__ invdeg,
                                                   float* __restrict__ diag) {
    __shared__ uint4 Xs[NSLOT];   // 128128 bytes static LDS
    const int t  = threadIdx.x;
    const int c0 = blockIdx.x * WCOLS;

    // zero the buffer (dummy row 8000 stays zero forever)
    for (int i = t; i < NSLOT; i += 1024) Xs[i] = make_uint4(0u, 0u, 0u, 0u);
    __syncthreads();
    if (t < WCOLS) {
        int c = c0 + t;
        float v = invdeg[c] * 1024.0f;   // scaled one-hot, weight pre-folded
        uint32_t hw = (uint32_t)__builtin_bit_cast(uint16_t, (_Float16)v);
        uint32_t word = hw << ((t & 1) * 16);
        uint4 w = make_uint4(0u, 0u, 0u, 0u);
        int wi = t >> 1;
        if      (wi == 0) w.x = word;
        else if (wi == 1) w.y = word;
        else if (wi == 2) w.z = word;
        else              w.w = word;
        Xs[c] = w;
    }

    // cache this thread's 8 slots in registers for all 16 steps
    uint32_t sc[8], sb[8], se[8];
    float sid[8];
#pragma unroll
    for (int q = 0; q < 8; ++q) {
        int i = q * 1024 + t;
        if (i < N_NODES) {
            uint32_t c = perm[i];
            sc[q] = c;
            sb[q] = poffs[i];
            se[q] = poffs[i + 1];
            sid[q] = invdeg[c];
        } else {
            sc[q] = 0xFFFFFFFFu; sb[q] = 0u; se[q] = 0u; sid[q] = 0.0f;
        }
    }
    __syncthreads();

    const char* base = (const char*)&Xs[0];

    for (int s = 0; s < WALK_LEN; ++s) {
        uint4 pend[8];
#pragma unroll
        for (int q = 0; q < 8; ++q) {
            if (sc[q] == 0xFFFFFFFFu) { pend[q] = make_uint4(0u, 0u, 0u, 0u); continue; }
            float a0 = 0.f, a1 = 0.f, a2 = 0.f, a3 = 0.f;
            float a4 = 0.f, a5 = 0.f, a6 = 0.f, a7 = 0.f;
            for (uint32_t e = sb[q]; e < se[q]; e += 4) {
                uint2 cc = *(const uint2*)(prows + e);   // 4 u16 row indices
#define EDGE_AT(R)                                                          \
                {   uint4 wv = *(const uint4*)(base + ((uint32_t)(R) << 4));\
                    half2_t h0 = __builtin_bit_cast(half2_t, wv.x);         \
                    half2_t h1 = __builtin_bit_cast(half2_t, wv.y);         \
                    half2_t h2 = __builtin_bit_cast(half2_t, wv.z);         \
                    half2_t h3 = __builtin_bit_cast(half2_t, wv.w);         \
                    a0 += (float)h0.x;  a1 += (float)h0.y;                  \
                    a2 += (float)h1.x;  a3 += (float)h1.y;                  \
                    a4 += (float)h2.x;  a5 += (float)h2.y;                  \
                    a6 += (float)h3.x;  a7 += (float)h3.y;                  \
                }
                EDGE_AT(cc.x & 0xFFFFu)  EDGE_AT(cc.x >> 16)
                EDGE_AT(cc.y & 0xFFFFu)  EDGE_AT(cc.y >> 16)
#undef EDGE_AT
            }
            uint32_t c = sc[q];
            uint32_t j = c - (uint32_t)c0;
            if (j < 8u) {   // this column's diagonal entry (undo the x1024 scaling)
                float dv = a0;
                dv = (j == 1u) ? a1 : dv;
                dv = (j == 2u) ? a2 : dv;
                dv = (j == 3u) ? a3 : dv;
                dv = (j == 4u) ? a4 : dv;
                dv = (j == 5u) ? a5 : dv;
                dv = (j == 6u) ? a6 : dv;
                dv = (j == 7u) ? a7 : dv;
                diag[c * WALK_LEN + s] = dv * (1.0f / 1024.0f);
            }
            float id = sid[q];
            half2_t h01, h23, h45, h67;
            h01.x = (_Float16)(a0 * id);  h01.y = (_Float16)(a1 * id);
            h23.x = (_Float16)(a2 * id);  h23.y = (_Float16)(a3 * id);
            h45.x = (_Float16)(a4 * id);  h45.y = (_Float16)(a5 * id);
            h67.x = (_Float16)(a6 * id);  h67.y = (_Float16)(a7 * id);
            pend[q].x = __builtin_bit_cast(uint32_t, h01);
            pend[q].y = __builtin_bit_cast(uint32_t, h23);
            pend[q].z = __builtin_bit_cast(uint32_t, h45);
            pend[q].w = __builtin_bit_cast(uint32_t, h67);
        }
        __syncthreads();   // all reads of old state done
#pragma unroll
        for (int q = 0; q < 8; ++q)
            if (sc[q] != 0xFFFFFFFFu) Xs[sc[q]] = pend[q];
        __syncthreads();   // new state visible
    }
}

// ---------------- K6: linear layer out = diag @ W^T + b ----------------
__global__ void k6_out(const float* __restrict__ diag, const float* __restrict__ W,
                       const float* __restrict__ b, float* __restrict__ out) {
    int i = blockIdx.x * 256 + threadIdx.x;
    if (i < N_NODES * OUT_DIM) {
        int n = i >> 3;
        int d = i & 7;
        float acc = b[d];
#pragma unroll
        for (int k = 0; k < WALK_LEN; ++k)
            acc += diag[n * WALK_LEN + k] * W[d * WALK_LEN + k];
        out[i] = acc;
    }
}

// ---------------- launcher ----------------
extern "C" void kernel_launch(void* const* d_in, const int* in_sizes, int n_in,
                              void* d_out, int out_size, void* d_ws, size_t ws_size,
                              hipStream_t stream) {
    const int*   ei = (const int*)d_in[0];     // [2, E] int32: rows then cols
    const float* rw = (const float*)d_in[2];   // [E] f32
    const float* W  = (const float*)d_in[3];   // [8,16] f32
    const float* b  = (const float*)d_in[4];   // [8] f32
    float* out = (float*)d_out;                // [N,8] f32

    // workspace carve-up (512-byte aligned slices)
    char* w = (char*)d_ws;
    auto alloc = [&](size_t bytes) -> char* {
        char* p = w;
        w += (bytes + 511) & ~(size_t)511;
        return p;
    };
    uint32_t* cnt    = (uint32_t*)alloc(N_NODES * 4);
    float*    invdeg = (float*)   alloc(N_NODES * 4);
    uint32_t* perm   = (uint32_t*)alloc(N_NODES * 4);
    uint32_t* rank   = (uint32_t*)alloc(N_NODES * 4);
    uint32_t* poffs  = (uint32_t*)alloc((N_NODES + 1) * 4);
    uint32_t* pcur   = (uint32_t*)alloc(N_NODES * 4);
    uint16_t* prows  = (uint16_t*)alloc(PADCAP * 2);
    float*    diag   = (float*)   alloc(N_NODES * WALK_LEN * 4);

    k0_init   <<<(PADCAP + 255) / 256, 256, 0, stream>>>(cnt, invdeg, prows);
    k1_count  <<<(N_EDGES + 255) / 256, 256, 0, stream>>>(ei, rw, cnt, invdeg);
    k2_sort   <<<1, 1024, 0, stream>>>(cnt, perm, rank);
    k3_scan   <<<1, 1024, 0, stream>>>(cnt, perm, poffs, pcur);
    k4_scatter<<<(N_EDGES + 255) / 256, 256, 0, stream>>>(ei, rank, pcur, prows);
    k5_walk   <<<N_NODES / WCOLS, 1024, 0, stream>>>(perm, poffs, prows, invdeg, diag);
    k6_out    <<<(N_NODES * OUT_DIM + 255) / 256, 256, 0, stream>>>(diag, W, b, out);
}

// Round 14
// 1014.206 us; speedup vs baseline: 2.0198x; 1.4091x over previous
//
#include <hip/hip_runtime.h>
#include <stdint.h>

// ---------------- problem constants (fixed by the reference) ----------------
#define N_NODES   8000
#define N_EDGES   128000
#define WALK_LEN  16
#define OUT_DIM   8

// ---------------- main-kernel layout constants ----------------
#define WCOLS     8                    // walk columns per block (f16x8 = 16B rows)
#define NSLOT     8008                 // 8000 real rows + dummy zero-row 8000 (+pad)
#define PADCAP    (N_EDGES + 4 * N_NODES)  // 160000: per-col pad-to-4 worst case

typedef _Float16 half2_t __attribute__((ext_vector_type(2)));

// ---------------- K0: init cnt/invdeg, fill prows with the dummy row ----------------
// All pad edges point at row 8000 (kept zero): a wave's pad lanes read the SAME
// address -> LDS broadcast, no bank conflict.
__global__ void k0_init(uint32_t* __restrict__ cnt, float* __restrict__ invdeg,
                        uint16_t* __restrict__ prows) {
    int i = blockIdx.x * 256 + threadIdx.x;
    if (i < PADCAP)  prows[i] = (uint16_t)8000;
    if (i < N_NODES) { cnt[i] = 0u; invdeg[i] = 1.0f; }
}

// ---------------- K1: in-degree count + invdeg scatter ----------------
// invdeg[r] = rw[e] for every edge with row r (all identical: 1/deg(r)) — benign race.
// Nodes with no out-edges keep invdeg=1.0, matching the reference's clip(deg,1).
__global__ void k1_count(const int* __restrict__ ei, const float* __restrict__ rw,
                         uint32_t* __restrict__ cnt, float* __restrict__ invdeg) {
    int e = blockIdx.x * 256 + threadIdx.x;
    if (e < N_EDGES) {
        int r = ei[e];
        int c = ei[N_EDGES + e];
        atomicAdd(&cnt[c], 1u);
        invdeg[r] = rw[e];
    }
}

// ---------------- K2: counting sort of columns by in-degree ----------------
// perm[slot] = col, rank[col] = slot.  Sorted order = wave-uniform trip counts.
__global__ __launch_bounds__(1024) void k2_sort(const uint32_t* __restrict__ cnt,
                                                uint32_t* __restrict__ perm,
                                                uint32_t* __restrict__ rank) {
    __shared__ uint32_t h[256];
    __shared__ uint32_t hoff[256];
    int t = threadIdx.x;
    if (t < 256) h[t] = 0u;
    __syncthreads();
    for (int i = t; i < N_NODES; i += 1024) {
        uint32_t d = cnt[i]; if (d > 255u) d = 255u;
        atomicAdd(&h[d], 1u);
    }
    __syncthreads();
    if (t == 0) {
        uint32_t run = 0;
        for (int b = 0; b < 256; ++b) { hoff[b] = run; run += h[b]; }
    }
    __syncthreads();
    for (int i = t; i < N_NODES; i += 1024) {
        uint32_t d = cnt[i]; if (d > 255u) d = 255u;
        uint32_t slot = atomicAdd(&hoff[d], 1u);
        perm[slot] = (uint32_t)i;
        rank[i] = slot;
    }
}

// ---------------- K3: exclusive scan of pad-to-4 degrees over perm order ----------------
__global__ __launch_bounds__(1024) void k3_scan(const uint32_t* __restrict__ cnt,
                                                const uint32_t* __restrict__ perm,
                                                uint32_t* __restrict__ poffs,
                                                uint32_t* __restrict__ pcur) {
    __shared__ uint32_t s[2][8192];   // 64 KB, Hillis-Steele double buffer
    int t = threadIdx.x;
    for (int i = t; i < 8192; i += 1024) {
        uint32_t v = 0u;
        if (i < N_NODES) v = (cnt[perm[i]] + 3u) & ~3u;   // pad each column to x4
        s[0][i] = v;
    }
    __syncthreads();
    int src = 0;
    for (int d = 1; d < 8192; d <<= 1) {
        for (int i = t; i < 8192; i += 1024) {
            uint32_t v = s[src][i];
            if (i >= d) v += s[src][i - d];
            s[src ^ 1][i] = v;
        }
        __syncthreads();
        src ^= 1;
    }
    for (int i = t; i < 8192; i += 1024) {
        if (i < N_NODES) {
            uint32_t ex = (i == 0) ? 0u : s[src][i - 1];
            poffs[i] = ex;
            pcur[i]  = ex;
        }
    }
    if (t == 0) poffs[N_NODES] = s[src][N_NODES - 1];
}

// ---------------- K4: scatter edges into permuted CSC (plain u16 row index) ------------
// Edge order within a column is arrival-random — measured BEST (round 12/13: ~8-9
// conflict-cyc/read vs 10.8 for the k4b stagger sort; correlated sorts are worse).
__global__ void k4_scatter(const int* __restrict__ ei, const uint32_t* __restrict__ rank,
                           uint32_t* __restrict__ pcur, uint16_t* __restrict__ prows) {
    int e = blockIdx.x * 256 + threadIdx.x;
    if (e < N_EDGES) {
        int r = ei[e];
        int c = ei[N_EDGES + e];
        uint32_t slot = rank[c];
        uint32_t pos  = atomicAdd(&pcur[slot], 1u);
        prows[pos] = (uint16_t)r;
    }
}

// ---------------- K5: 16-step walk, 8 cols/block, f16 PACKED accumulate ------------
// State X~ = 1024 * invdeg ⊙ X in f16x8 rows (16B), SINGLE LDS buffer (128128 B).
// Gather: 1 ds_read_b128 + 4 v_pk_add_f16 per edge (f16 accumulation — safe:
// |sum| <= 17*1024 << 65504; noise ~0.1%/step, under the 2^-10 absmax floor).
// Steps 1..15: full sweep + pk_mul_f16 write-back. Step 16: diag-only — each block
// needs just its own 8 columns' gathers (~140 edges), no state write (-1/16 reads).
__global__ __launch_bounds__(1024, 4) void k5_walk(const uint32_t* __restrict__ perm,
                                                   const uint32_t* __restrict__ poffs,
                                                   const uint16_t* __restrict__ prows,
                                                   const float* __restrict__ invdeg,
                                                   float* __restrict__ diag) {
    __shared__ uint4 Xs[NSLOT];   // 128128 bytes static LDS
    const int t  = threadIdx.x;
    const int c0 = blockIdx.x * WCOLS;

    // zero the buffer (dummy row 8000 stays zero forever)
    for (int i = t; i < NSLOT; i += 1024) Xs[i] = make_uint4(0u, 0u, 0u, 0u);
    __syncthreads();
    if (t < WCOLS) {
        int c = c0 + t;
        float v = invdeg[c] * 1024.0f;   // scaled one-hot, weight pre-folded
        uint32_t hw = (uint32_t)__builtin_bit_cast(uint16_t, (_Float16)v);
        uint32_t word = hw << ((t & 1) * 16);
        uint4 w = make_uint4(0u, 0u, 0u, 0u);
        int wi = t >> 1;
        if      (wi == 0) w.x = word;
        else if (wi == 1) w.y = word;
        else if (wi == 2) w.z = word;
        else              w.w = word;
        Xs[c] = w;
    }

    // cache this thread's 8 slots in registers for all steps
    uint32_t sc[8], sb[8], se[8], sip[8];
#pragma unroll
    for (int q = 0; q < 8; ++q) {
        int i = q * 1024 + t;
        if (i < N_NODES) {
            uint32_t c = perm[i];
            sc[q] = c;
            sb[q] = poffs[i];
            se[q] = poffs[i + 1];
            uint32_t h = (uint32_t)__builtin_bit_cast(uint16_t, (_Float16)invdeg[c]);
            sip[q] = h | (h << 16);   // f16 invdeg duplicated for pk_mul
        } else {
            sc[q] = 0xFFFFFFFFu; sb[q] = 0u; se[q] = 0u; sip[q] = 0u;
        }
    }
    __syncthreads();

    const char* base = (const char*)&Xs[0];
    const half2_t hz = {(_Float16)0.0f, (_Float16)0.0f};

#define GATHER_BODY(Q)                                                      \
    for (uint32_t e = sb[Q]; e < se[Q]; e += 4) {                           \
        uint2 cc = *(const uint2*)(prows + e);                              \
        {   uint4 wv = *(const uint4*)(base + ((cc.x & 0xFFFFu) << 4));     \
            p0 += __builtin_bit_cast(half2_t, wv.x);                        \
            p1 += __builtin_bit_cast(half2_t, wv.y);                        \
            p2 += __builtin_bit_cast(half2_t, wv.z);                        \
            p3 += __builtin_bit_cast(half2_t, wv.w); }                      \
        {   uint4 wv = *(const uint4*)(base + ((cc.x >> 16) << 4));         \
            p0 += __builtin_bit_cast(half2_t, wv.x);                        \
            p1 += __builtin_bit_cast(half2_t, wv.y);                        \
            p2 += __builtin_bit_cast(half2_t, wv.z);                        \
            p3 += __builtin_bit_cast(half2_t, wv.w); }                      \
        {   uint4 wv = *(const uint4*)(base + ((cc.y & 0xFFFFu) << 4));     \
            p0 += __builtin_bit_cast(half2_t, wv.x);                        \
            p1 += __builtin_bit_cast(half2_t, wv.y);                        \
            p2 += __builtin_bit_cast(half2_t, wv.z);                        \
            p3 += __builtin_bit_cast(half2_t, wv.w); }                      \
        {   uint4 wv = *(const uint4*)(base + ((cc.y >> 16) << 4));         \
            p0 += __builtin_bit_cast(half2_t, wv.x);                        \
            p1 += __builtin_bit_cast(half2_t, wv.y);                        \
            p2 += __builtin_bit_cast(half2_t, wv.z);                        \
            p3 += __builtin_bit_cast(half2_t, wv.w); }                      \
    }

#define DIAG_SELECT(J)                                                      \
    half2_t sp = p0;                                                        \
    sp = ((J) >> 1 == 1u) ? p1 : sp;                                        \
    sp = ((J) >> 1 == 2u) ? p2 : sp;                                        \
    sp = ((J) >> 1 == 3u) ? p3 : sp;                                        \
    float dv = ((J) & 1u) ? (float)sp.y : (float)sp.x;

    for (int s = 0; s < WALK_LEN - 1; ++s) {   // 15 full sweeps
        uint4 pend[8];
#pragma unroll
        for (int q = 0; q < 8; ++q) {
            if (sc[q] == 0xFFFFFFFFu) { pend[q] = make_uint4(0u, 0u, 0u, 0u); continue; }
            half2_t p0 = hz, p1 = hz, p2 = hz, p3 = hz;
            GATHER_BODY(q)
            uint32_t c = sc[q];
            uint32_t j = c - (uint32_t)c0;
            if (j < 8u) {   // own-column diagonal (undo the x1024 scaling)
                DIAG_SELECT(j)
                diag[c * WALK_LEN + s] = dv * (1.0f / 1024.0f);
            }
            half2_t idh = __builtin_bit_cast(half2_t, sip[q]);
            pend[q].x = __builtin_bit_cast(uint32_t, p0 * idh);
            pend[q].y = __builtin_bit_cast(uint32_t, p1 * idh);
            pend[q].z = __builtin_bit_cast(uint32_t, p2 * idh);
            pend[q].w = __builtin_bit_cast(uint32_t, p3 * idh);
        }
        __syncthreads();   // all reads of old state done
#pragma unroll
        for (int q = 0; q < 8; ++q)
            if (sc[q] != 0xFFFFFFFFu) Xs[sc[q]] = pend[q];
        __syncthreads();   // new state visible
    }

    // final step (s = 15): diag only — just this block's own 8 columns
#pragma unroll
    for (int q = 0; q < 8; ++q) {
        uint32_t c = sc[q];
        uint32_t j = c - (uint32_t)c0;
        if (sc[q] != 0xFFFFFFFFu && j < 8u) {
            half2_t p0 = hz, p1 = hz, p2 = hz, p3 = hz;
            GATHER_BODY(q)
            DIAG_SELECT(j)
            diag[c * WALK_LEN + (WALK_LEN - 1)] = dv * (1.0f / 1024.0f);
        }
    }
#undef GATHER_BODY
#undef DIAG_SELECT
}

// ---------------- K6: linear layer out = diag @ W^T + b ----------------
__global__ void k6_out(const float* __restrict__ diag, const float* __restrict__ W,
                       const float* __restrict__ b, float* __restrict__ out) {
    int i = blockIdx.x * 256 + threadIdx.x;
    if (i < N_NODES * OUT_DIM) {
        int n = i >> 3;
        int d = i & 7;
        float acc = b[d];
#pragma unroll
        for (int k = 0; k < WALK_LEN; ++k)
            acc += diag[n * WALK_LEN + k] * W[d * WALK_LEN + k];
        out[i] = acc;
    }
}

// ---------------- launcher ----------------
extern "C" void kernel_launch(void* const* d_in, const int* in_sizes, int n_in,
                              void* d_out, int out_size, void* d_ws, size_t ws_size,
                              hipStream_t stream) {
    const int*   ei = (const int*)d_in[0];     // [2, E] int32: rows then cols
    const float* rw = (const float*)d_in[2];   // [E] f32
    const float* W  = (const float*)d_in[3];   // [8,16] f32
    const float* b  = (const float*)d_in[4];   // [8] f32
    float* out = (float*)d_out;                // [N,8] f32

    // workspace carve-up (512-byte aligned slices)
    char* w = (char*)d_ws;
    auto alloc = [&](size_t bytes) -> char* {
        char* p = w;
        w += (bytes + 511) & ~(size_t)511;
        return p;
    };
    uint32_t* cnt    = (uint32_t*)alloc(N_NODES * 4);
    float*    invdeg = (float*)   alloc(N_NODES * 4);
    uint32_t* perm   = (uint32_t*)alloc(N_NODES * 4);
    uint32_t* rank   = (uint32_t*)alloc(N_NODES * 4);
    uint32_t* poffs  = (uint32_t*)alloc((N_NODES + 1) * 4);
    uint32_t* pcur   = (uint32_t*)alloc(N_NODES * 4);
    uint16_t* prows  = (uint16_t*)alloc(PADCAP * 2);
    float*    diag   = (float*)   alloc(N_NODES * WALK_LEN * 4);

    k0_init   <<<(PADCAP + 255) / 256, 256, 0, stream>>>(cnt, invdeg, prows);
    k1_count  <<<(N_EDGES + 255) / 256, 256, 0, stream>>>(ei, rw, cnt, invdeg);
    k2_sort   <<<1, 1024, 0, stream>>>(cnt, perm, rank);
    k3_scan   <<<1, 1024, 0, stream>>>(cnt, perm, poffs, pcur);
    k4_scatter<<<(N_EDGES + 255) / 256, 256, 0, stream>>>(ei, rank, pcur, prows);
    k5_walk   <<<N_NODES / WCOLS, 1024, 0, stream>>>(perm, poffs, prows, invdeg, diag);
    k6_out    <<<(N_NODES * OUT_DIM + 255) / 256, 256, 0, stream>>>(diag, W, b, out);
}